// Round 1
// baseline (192.496 us; speedup 1.0000x reference)
//
#include <hip/hip_runtime.h>

#define NCH 128
#define DIM_IN 1152
#define DIM_OUT 2048
#define VW 2   // channels per thread (float2 loads/stores)

// ---------------------------------------------------------------------------
// constexpr replication of the Python CG-table construction
// ---------------------------------------------------------------------------
struct CD { double re, im; };
constexpr CD operator+(CD a, CD b) { return {a.re + b.re, a.im + b.im}; }
constexpr CD operator*(CD a, CD b) {
    return {a.re * b.re - a.im * b.im, a.re * b.im + a.im * b.re};
}
constexpr CD cmuls(double s, CD a) { return {s * a.re, s * a.im}; }
constexpr CD cconj(CD a) { return {a.re, -a.im}; }

constexpr double cfact(int n) {
    double r = 1.0;
    for (int i = 2; i <= n; ++i) r *= (double)i;
    return r;
}
constexpr double cfabs(double x) { return x < 0 ? -x : x; }
constexpr double csqrt(double x) {
    if (x <= 0) return 0.0;
    double r = x > 1.0 ? x : 1.0;
    for (int it = 0; it < 100; ++it) r = 0.5 * (r + x / r);
    return r;
}

struct CTab { double v[5][5][7]; };   // su2 CG: [2*j1+1][2*j2+1][2*j3+1], j1,j2<=2, j3<=3
constexpr CTab su2cg(int j1, int j2, int j3) {
    CTab C{};
    double pj = csqrt((2.0 * j3 + 1.0) * cfact(j3 + j1 - j2) * cfact(j3 - j1 + j2) *
                      cfact(j1 + j2 - j3) / cfact(j1 + j2 + j3 + 1));
    for (int m1 = -j1; m1 <= j1; ++m1) {
        for (int m2 = -j2; m2 <= j2; ++m2) {
            int m3 = m1 + m2;
            if (m3 < -j3 || m3 > j3) continue;
            double pm = csqrt(cfact(j3 + m3) * cfact(j3 - m3) * cfact(j1 - m1) *
                              cfact(j1 + m1) * cfact(j2 - m2) * cfact(j2 + m2));
            double s = 0.0;
            for (int v = 0; v <= j1 + j2 - j3; ++v) {
                int a = j1 + j2 - j3 - v;
                int b = j1 - m1 - v;
                int c = j2 + m2 - v;
                int d = j3 - j2 + m1 + v;
                int e = j3 - j1 - m2 + v;
                if (a < 0 || b < 0 || c < 0 || d < 0 || e < 0) continue;
                double t = 1.0 / (cfact(v) * cfact(a) * cfact(b) * cfact(c) * cfact(d) * cfact(e));
                s += (v & 1) ? -t : t;
            }
            C.v[m1 + j1][m2 + j2][m3 + j3] = pj * pm * s;
        }
    }
    return C;
}

struct QMat { CD v[7][7]; };
constexpr QMat qmat(int l) {
    QMat q{};
    double s2 = csqrt(0.5);
    for (int m = -l; m < 0; ++m) {
        q.v[l + m][l - m] = CD{s2, 0.0};      // col l + |m|
        q.v[l + m][l + m] = CD{0.0, -s2};     // col l - |m|
    }
    q.v[l][l] = CD{1.0, 0.0};
    for (int m = 1; m <= l; ++m) {
        double sg = (m & 1) ? -1.0 : 1.0;     // (-1)^m
        q.v[l + m][l + m] = CD{sg * s2, 0.0};
        q.v[l + m][l - m] = CD{0.0, sg * s2};
    }
    // multiply by (-1j)^l
    CD f = (l == 0) ? CD{1, 0} : (l == 1) ? CD{0, -1} : (l == 2) ? CD{-1, 0} : CD{0, 1};
    for (int r = 0; r < 2 * l + 1; ++r)
        for (int c = 0; c < 2 * l + 1; ++c) q.v[r][c] = f * q.v[r][c];
    return q;
}

struct CGTab { float v[5][5][7]; };
constexpr CGTab realcg(int l1, int l2, int l3) {
    CTab C = su2cg(l1, l2, l3);
    QMat q1 = qmat(l1), q2 = qmat(l2), q3 = qmat(l3);
    const int n1 = 2 * l1 + 1, n2 = 2 * l2 + 1, n3 = 2 * l3 + 1;
    // staged einsum 'abc,ai,bj,ck->ijk' with conj on the third q
    CD T1[5][5][7]{};
    for (int i = 0; i < n1; ++i)
        for (int b = 0; b < n2; ++b)
            for (int c = 0; c < n3; ++c) {
                CD s{};
                for (int a = 0; a < n1; ++a) {
                    double cv = C.v[a][b][c];
                    if (cv != 0.0) s = s + cmuls(cv, q1.v[a][i]);
                }
                T1[i][b][c] = s;
            }
    CD T2[5][5][7]{};
    for (int i = 0; i < n1; ++i)
        for (int j = 0; j < n2; ++j)
            for (int c = 0; c < n3; ++c) {
                CD s{};
                for (int b = 0; b < n2; ++b) s = s + T1[i][b][c] * q2.v[b][j];
                T2[i][j][c] = s;
            }
    CD R[5][5][7]{};
    double sre = 0.0, sim = 0.0;
    for (int i = 0; i < n1; ++i)
        for (int j = 0; j < n2; ++j)
            for (int k = 0; k < n3; ++k) {
                CD s{};
                for (int c = 0; c < n3; ++c) s = s + T2[i][j][c] * cconj(q3.v[c][k]);
                R[i][j][k] = s;
                sre += cfabs(s.re);
                sim += cfabs(s.im);
            }
    CGTab out{};
    bool use_re = (sre >= sim);
    for (int i = 0; i < n1; ++i)
        for (int j = 0; j < n2; ++j)
            for (int k = 0; k < n3; ++k)
                out.v[i][j][k] = (float)(use_re ? R[i][j][k].re : R[i][j][k].im);
    return out;
}

// COUPLINGS order (lo,l1,l2); CG_TABLE key is (l1,l2,lo) -> realcg(l1,l2,lo)
constexpr CGTab CG00 = realcg(0, 0, 0);  // (0,0,0)
constexpr CGTab CG01 = realcg(1, 1, 0);  // (0,1,1)
constexpr CGTab CG02 = realcg(2, 2, 0);  // (0,2,2)
constexpr CGTab CG03 = realcg(0, 1, 1);  // (1,0,1)
constexpr CGTab CG04 = realcg(1, 0, 1);  // (1,1,0)
constexpr CGTab CG05 = realcg(1, 1, 1);  // (1,1,1)
constexpr CGTab CG06 = realcg(1, 2, 1);  // (1,1,2)
constexpr CGTab CG07 = realcg(2, 1, 1);  // (1,2,1)
constexpr CGTab CG08 = realcg(2, 2, 1);  // (1,2,2)
constexpr CGTab CG09 = realcg(0, 2, 2);  // (2,0,2)
constexpr CGTab CG10 = realcg(1, 1, 2);  // (2,1,1)
constexpr CGTab CG11 = realcg(1, 2, 2);  // (2,1,2)
constexpr CGTab CG12 = realcg(2, 0, 2);  // (2,2,0)
constexpr CGTab CG13 = realcg(2, 1, 2);  // (2,2,1)
constexpr CGTab CG14 = realcg(2, 2, 2);  // (2,2,2)
constexpr CGTab CG15 = realcg(1, 2, 3);  // (3,1,2)
constexpr CGTab CG16 = realcg(2, 1, 3);  // (3,2,1)
constexpr CGTab CG17 = realcg(2, 2, 3);  // (3,2,2)

constexpr CGTab CGS[18] = {CG00, CG01, CG02, CG03, CG04, CG05, CG06, CG07, CG08,
                           CG09, CG10, CG11, CG12, CG13, CG14, CG15, CG16, CG17};

// ---------------------------------------------------------------------------
// device kernel
// ---------------------------------------------------------------------------
// Input row layout per batch element (9 rows x 128 ch):  r0: l0m0; r1-3: l1; r4-8: l2
// Output row layout (16 rows x 128 ch): r0: l0; r1-3: l1; r4-8: l2; r9-15: l3

template <int CIDX, int LO, int L1, int L2>
__device__ __forceinline__ void coup(const float (&xin)[9][VW], float (&acc)[16][VW],
                                     const float (&mixv)[18][VW]) {
    constexpr int rb1 = (L1 == 0) ? 0 : ((L1 == 1) ? 1 : 4);
    constexpr int rb2 = (L2 == 0) ? 0 : ((L2 == 1) ? 1 : 4);
    constexpr int ob  = (LO == 0) ? 0 : ((LO == 1) ? 1 : ((LO == 2) ? 4 : 9));
    float tk[2 * LO + 1][VW];
#pragma unroll
    for (int k = 0; k < 2 * LO + 1; ++k)
#pragma unroll
        for (int c = 0; c < VW; ++c) tk[k][c] = 0.0f;
#pragma unroll
    for (int i = 0; i < 2 * L1 + 1; ++i) {
#pragma unroll
        for (int j = 0; j < 2 * L2 + 1; ++j) {
            float p[VW];
#pragma unroll
            for (int c = 0; c < VW; ++c) p[c] = xin[rb1 + i][c] * xin[rb2 + j][c];
#pragma unroll
            for (int k = 0; k < 2 * LO + 1; ++k) {
                const float cg = CGS[CIDX].v[i][j][k];  // compile-time constant after unroll
                if (cg != 0.0f) {
#pragma unroll
                    for (int c = 0; c < VW; ++c) tk[k][c] += cg * p[c];
                }
            }
        }
    }
#pragma unroll
    for (int k = 0; k < 2 * LO + 1; ++k)
#pragma unroll
        for (int c = 0; c < VW; ++c) acc[ob + k][c] += mixv[CIDX][c] * tk[k][c];
}

__global__ __launch_bounds__(256) void selfmix_kernel(
    const float* __restrict__ x, const float* __restrict__ keep,
    const float* __restrict__ mix, float* __restrict__ out, int nb) {
    int t = blockIdx.x * 256 + threadIdx.x;
    int b = t >> 6;           // NCH/VW = 64 vector-channel slots per batch element
    int nv = t & 63;
    if (b >= nb) return;
    int n0 = nv * VW;

    const float* xb = x + (size_t)b * DIM_IN + n0;
    float xin[9][VW];
#pragma unroll
    for (int r = 0; r < 9; ++r) {
        float2 v = *reinterpret_cast<const float2*>(xb + r * NCH);
        xin[r][0] = v.x;
        xin[r][1] = v.y;
    }
    float mixv[18][VW];
#pragma unroll
    for (int i = 0; i < 18; ++i) {
        float2 v = *reinterpret_cast<const float2*>(mix + i * NCH + n0);
        mixv[i][0] = 0.5f * v.x;   // fold the 0.5 factor into the mix coefficient
        mixv[i][1] = 0.5f * v.y;
    }
    float keepv[3][VW];
#pragma unroll
    for (int l = 0; l < 3; ++l) {
        float2 v = *reinterpret_cast<const float2*>(keep + l * NCH + n0);
        keepv[l][0] = v.x;
        keepv[l][1] = v.y;
    }

    float acc[16][VW];
#pragma unroll
    for (int r = 0; r < 16; ++r)
#pragma unroll
        for (int c = 0; c < VW; ++c) acc[r][c] = 0.0f;

    // keep terms: out[l] += xs[l] * keep_coeff[l]
#pragma unroll
    for (int c = 0; c < VW; ++c) acc[0][c] = xin[0][c] * keepv[0][c];
#pragma unroll
    for (int r = 1; r < 4; ++r)
#pragma unroll
        for (int c = 0; c < VW; ++c) acc[r][c] = xin[r][c] * keepv[1][c];
#pragma unroll
    for (int r = 4; r < 9; ++r)
#pragma unroll
        for (int c = 0; c < VW; ++c) acc[r][c] = xin[r][c] * keepv[2][c];

    // 18 couplings (lo,l1,l2) in reference order
    coup<0, 0, 0, 0>(xin, acc, mixv);
    coup<1, 0, 1, 1>(xin, acc, mixv);
    coup<2, 0, 2, 2>(xin, acc, mixv);
    coup<3, 1, 0, 1>(xin, acc, mixv);
    coup<4, 1, 1, 0>(xin, acc, mixv);
    coup<5, 1, 1, 1>(xin, acc, mixv);
    coup<6, 1, 1, 2>(xin, acc, mixv);
    coup<7, 1, 2, 1>(xin, acc, mixv);
    coup<8, 1, 2, 2>(xin, acc, mixv);
    coup<9, 2, 0, 2>(xin, acc, mixv);
    coup<10, 2, 1, 1>(xin, acc, mixv);
    coup<11, 2, 1, 2>(xin, acc, mixv);
    coup<12, 2, 2, 0>(xin, acc, mixv);
    coup<13, 2, 2, 1>(xin, acc, mixv);
    coup<14, 2, 2, 2>(xin, acc, mixv);
    coup<15, 3, 1, 2>(xin, acc, mixv);
    coup<16, 3, 2, 1>(xin, acc, mixv);
    coup<17, 3, 2, 2>(xin, acc, mixv);

    float* ob = out + (size_t)b * DIM_OUT + n0;
#pragma unroll
    for (int r = 0; r < 16; ++r) {
        float2 v;
        v.x = acc[r][0];
        v.y = acc[r][1];
        *reinterpret_cast<float2*>(ob + r * NCH) = v;
    }
}

extern "C" void kernel_launch(void* const* d_in, const int* in_sizes, int n_in,
                              void* d_out, int out_size, void* d_ws, size_t ws_size,
                              hipStream_t stream) {
    const float* x = (const float*)d_in[0];
    const float* keep = (const float*)d_in[1];
    const float* mix = (const float*)d_in[2];
    float* out = (float*)d_out;
    int nb = in_sizes[0] / DIM_IN;               // 16384
    int total = nb * (NCH / VW);                 // threads
    int blocks = (total + 255) / 256;
    hipLaunchKernelGGL(selfmix_kernel, dim3(blocks), dim3(256), 0, stream,
                       x, keep, mix, out, nb);
}